// Round 3
// baseline (554.141 us; speedup 1.0000x reference)
//
#include <hip/hip_runtime.h>
#include <math.h>

// Problem constants (CBOW_5205500363137)
#define BB     65536
#define KK     10
#define EE     128
#define NBLK   2048   // main-kernel grid
#define ITERS  4      // rows per half-wave: 2048 blocks * 8 halfwaves * 4 = 65536

typedef float f4 __attribute__((ext_vector_type(4)));

// Non-temporal 16B load (streaming data: dropout masks are use-once; keep L2
// for the V/U embedding tables which are gathered randomly and re-used).
__device__ __forceinline__ f4 ldnt(const float* p) {
    return __builtin_nontemporal_load((const f4*)p);
}
__device__ __forceinline__ f4 ldg4(const float* p) {
    return *(const f4*)p;
}

__device__ __forceinline__ float log_sigmoid_f(float x) {
    // log(sigmoid(x)) = min(x, 0) - log1p(exp(-|x|))   (numerically stable)
    return fminf(x, 0.0f) - log1pf(expf(-fabsf(x)));
}

__global__ __launch_bounds__(256) void cbow_main(
    const int*   __restrict__ ctx_words,   // [B]
    const int*   __restrict__ tgt_words,   // [B]
    const int*   __restrict__ neg_words,   // [B,K]
    const float* __restrict__ V_emb,       // [VOCAB,E]
    const float* __restrict__ U_emb,       // [VOCAB,E]
    const float* __restrict__ mask_v,      // [B,E]
    const float* __restrict__ mask_u,      // [B,E]
    const float* __restrict__ mask_neg,    // [B,K,E]
    double*      __restrict__ partials)    // [NBLK]
{
    const int t    = threadIdx.x;
    const int sub  = t >> 5;    // 0..7: half-wave id within block
    const int lane = t & 31;    // lane within the 32-lane half-wave

    // ---- Phase 0: ALL index loads for the 4 rows up front (12 independent) ----
    int rows[ITERS], ctx[ITERS], tgt[ITERS], nidx[ITERS];
#pragma unroll
    for (int gi = 0; gi < ITERS; ++gi) {
        rows[gi] = (blockIdx.x * ITERS + gi) * 8 + sub;
        ctx[gi]  = ctx_words[rows[gi]];
        tgt[gi]  = tgt_words[rows[gi]];
        // lanes 0..9 hold the 10 negative indices; broadcast later via shfl
        nidx[gi] = neg_words[(size_t)rows[gi] * KK + (lane < KK ? lane : 0)];
    }

    // ---- Phase 1: v = V[ctx]*mask_v for all rows (8 independent f4 loads) ----
    f4 v[ITERS];
#pragma unroll
    for (int gi = 0; gi < ITERS; ++gi) {
        const f4 ve = ldg4(V_emb  + (size_t)ctx[gi]  * EE + lane * 4);
        const f4 mv = ldnt(mask_v + (size_t)rows[gi] * EE + lane * 4);
        v[gi] = ve * mv;
    }

    // ---- Phase 2: pos partials for all rows (8 independent f4 loads) ----
    float pos[ITERS], neg[ITERS];
#pragma unroll
    for (int gi = 0; gi < ITERS; ++gi) {
        const f4 ue = ldg4(U_emb  + (size_t)tgt[gi]  * EE + lane * 4);
        const f4 mu = ldnt(mask_u + (size_t)rows[gi] * EE + lane * 4);
        const f4 up = ue * mu;
        pos[gi] = fmaf(up.x, v[gi].x, fmaf(up.y, v[gi].y,
                  fmaf(up.z, v[gi].z, up.w * v[gi].w)));
        neg[gi] = 0.0f;
    }

    // ---- Phase 3: k outer, rows inner -> 8 independent loads per k-step ----
#pragma unroll
    for (int k = 0; k < KK; ++k) {
#pragma unroll
        for (int gi = 0; gi < ITERS; ++gi) {
            const int nk = __shfl(nidx[gi], k, 32);
            const f4 ne = ldg4(U_emb + (size_t)nk * EE + lane * 4);
            const f4 mn = ldnt(mask_neg + ((size_t)rows[gi] * KK + k) * EE + lane * 4);
            const f4 np = ne * mn;
            neg[gi] = fmaf(np.x, v[gi].x, neg[gi]);
            neg[gi] = fmaf(np.y, v[gi].y, neg[gi]);
            neg[gi] = fmaf(np.z, v[gi].z, neg[gi]);
            neg[gi] = fmaf(np.w, v[gi].w, neg[gi]);
        }
    }

    // ---- Phase 4: half-wave reductions + loss ----
    double local = 0.0;
#pragma unroll
    for (int gi = 0; gi < ITERS; ++gi) {
        float p = pos[gi], n = neg[gi];
#pragma unroll
        for (int m = 16; m >= 1; m >>= 1) {
            p += __shfl_xor(p, m, 64);
            n += __shfl_xor(n, m, 64);
        }
        if (lane == 0)
            local += (double)(log_sigmoid_f(p) + log_sigmoid_f(-n));
    }

    // Block reduction: 8 half-wave leaders -> one double per block
    __shared__ double sbuf[8];
    if (lane == 0) sbuf[sub] = local;
    __syncthreads();
    if (t == 0) {
        double s = 0.0;
#pragma unroll
        for (int i = 0; i < 8; ++i) s += sbuf[i];
        partials[blockIdx.x] = s;
    }
}

__global__ __launch_bounds__(256) void cbow_reduce(
    const double* __restrict__ partials, float* __restrict__ out)
{
    __shared__ double sbuf[256];
    double s = 0.0;
    for (int i = threadIdx.x; i < NBLK; i += 256) s += partials[i];
    sbuf[threadIdx.x] = s;
    __syncthreads();
    for (int stride = 128; stride > 0; stride >>= 1) {
        if (threadIdx.x < stride) sbuf[threadIdx.x] += sbuf[threadIdx.x + stride];
        __syncthreads();
    }
    if (threadIdx.x == 0) out[0] = (float)(-sbuf[0] / (double)BB);
}

extern "C" void kernel_launch(void* const* d_in, const int* in_sizes, int n_in,
                              void* d_out, int out_size, void* d_ws, size_t ws_size,
                              hipStream_t stream) {
    const int*   ctx_words = (const int*)  d_in[0];
    const int*   tgt_words = (const int*)  d_in[1];
    const int*   neg_words = (const int*)  d_in[2];
    const float* V_emb     = (const float*)d_in[3];
    const float* U_emb     = (const float*)d_in[4];
    const float* mask_v    = (const float*)d_in[5];
    const float* mask_u    = (const float*)d_in[6];
    const float* mask_neg  = (const float*)d_in[7];
    float*       out       = (float*)d_out;
    double*      partials  = (double*)d_ws;   // needs NBLK*8 = 16 KiB of ws

    cbow_main<<<NBLK, 256, 0, stream>>>(ctx_words, tgt_words, neg_words,
                                        V_emb, U_emb, mask_v, mask_u, mask_neg,
                                        partials);
    cbow_reduce<<<1, 256, 0, stream>>>(partials, out);
}

// Round 4
// 546.916 us; speedup vs baseline: 1.0132x; 1.0132x over previous
//
#include <hip/hip_runtime.h>
#include <math.h>

// Problem constants (CBOW_5205500363137)
#define BB     65536
#define KK     10
#define EE     128
#define NBLK   2048   // main-kernel grid
#define ITERS  4      // rows per half-wave: 2048 * 8 * 4 = 65536

typedef float f4     __attribute__((ext_vector_type(4)));
typedef int   int4v  __attribute__((ext_vector_type(4)));

// Raw buffer load with explicit cache policy (CK-style direct intrinsic bind).
// cpol bits on gfx940+/gfx950: bit0=SC0, bit1=NT, bit4=SC1.
// SC1|NT (0x12): non-temporal + no MALL allocation -> the use-once mask
// streams don't evict the V/U embedding tables from Infinity Cache.
extern "C" __device__ f4 llvm_raw_buffer_load_v4f32(int4v rsrc, int voffset,
                                                    int soffset, int cpol)
    __asm("llvm.amdgcn.raw.buffer.load.v4f32");

__device__ __forceinline__ int4v make_srd(const void* p) {
    int4v r;
    uintptr_t a = (uintptr_t)p;
    r.x = (int)(a & 0xFFFFFFFFu);
    r.y = (int)(a >> 32);          // stride = 0
    r.z = -1;                      // num_records = 0xFFFFFFFF (bounds check off)
    r.w = 0x00020000;              // raw untyped dword access
    return r;
}

// Streaming (use-once) load: bypass MALL, evict-first in L2.
__device__ __forceinline__ f4 ld_stream(const float* base, int elem_off) {
    return llvm_raw_buffer_load_v4f32(make_srd(base), elem_off * 4, 0, 0x12);
}
// Normal cached load (embedding tables: reused, keep resident in L2/L3).
__device__ __forceinline__ f4 ldg4(const float* p) {
    return *(const f4*)p;
}

__device__ __forceinline__ float log_sigmoid_f(float x) {
    // log(sigmoid(x)) = min(x, 0) - log1p(exp(-|x|))   (numerically stable)
    return fminf(x, 0.0f) - log1pf(expf(-fabsf(x)));
}

__global__ __launch_bounds__(256) void cbow_main(
    const int*   __restrict__ ctx_words,   // [B]
    const int*   __restrict__ tgt_words,   // [B]
    const int*   __restrict__ neg_words,   // [B,K]
    const float* __restrict__ V_emb,       // [VOCAB,E]
    const float* __restrict__ U_emb,       // [VOCAB,E]
    const float* __restrict__ mask_v,      // [B,E]
    const float* __restrict__ mask_u,      // [B,E]
    const float* __restrict__ mask_neg,    // [B,K,E]
    double*      __restrict__ partials)    // [NBLK]
{
    const int t    = threadIdx.x;
    const int sub  = t >> 5;    // 0..7: half-wave id within block (one row each)
    const int lane = t & 31;    // lane within the 32-lane half-wave

    double local = 0.0;

    for (int gi = 0; gi < ITERS; ++gi) {
        const int row = (blockIdx.x * ITERS + gi) * 8 + sub;

        const int ctx = ctx_words[row];
        const int tgt = tgt_words[row];
        // lanes 0..9 hold the 10 negative indices; broadcast via shfl below
        const int nidx = neg_words[(size_t)row * KK + (lane < KK ? lane : 0)];

        // v = V_emb[ctx] * mask_v[row]   (each lane holds 4 consecutive floats)
        const f4 ve = ldg4(V_emb + (size_t)ctx * EE + lane * 4);
        const f4 mv = ld_stream(mask_v, row * EE + lane * 4);
        const f4 v  = ve * mv;

        // u = U_emb[tgt] * mask_u[row]; pos partial = dot(u, v)
        const f4 ue = ldg4(U_emb + (size_t)tgt * EE + lane * 4);
        const f4 mu = ld_stream(mask_u, row * EE + lane * 4);
        const f4 up = ue * mu;
        float posp = fmaf(up.x, v.x, fmaf(up.y, v.y, fmaf(up.z, v.z, up.w * v.w)));

        // negp = sum_k dot(U_emb[nk]*mask_neg[row,k], v)
        float negp = 0.0f;
#pragma unroll
        for (int k = 0; k < KK; ++k) {
            const int nk = __shfl(nidx, k, 32);
            const f4 ne = ldg4(U_emb + (size_t)nk * EE + lane * 4);
            const f4 mn = ld_stream(mask_neg, (row * KK + k) * EE + lane * 4);
            const f4 np = ne * mn;
            negp = fmaf(np.x, v.x, negp);
            negp = fmaf(np.y, v.y, negp);
            negp = fmaf(np.z, v.z, negp);
            negp = fmaf(np.w, v.w, negp);
        }

        // Reduce within the 32-lane half (xor masks <=16 stay inside each half)
        float pos = posp, neg = negp;
#pragma unroll
        for (int m = 16; m >= 1; m >>= 1) {
            pos += __shfl_xor(pos, m, 64);
            neg += __shfl_xor(neg, m, 64);
        }

        if (lane == 0) {
            local += (double)(log_sigmoid_f(pos) + log_sigmoid_f(-neg));
        }
    }

    // Block reduction: 8 half-wave leaders -> one double per block
    __shared__ double sbuf[8];
    if (lane == 0) sbuf[sub] = local;
    __syncthreads();
    if (t == 0) {
        double s = 0.0;
#pragma unroll
        for (int i = 0; i < 8; ++i) s += sbuf[i];
        partials[blockIdx.x] = s;
    }
}

__global__ __launch_bounds__(256) void cbow_reduce(
    const double* __restrict__ partials, float* __restrict__ out)
{
    __shared__ double sbuf[256];
    double s = 0.0;
    for (int i = threadIdx.x; i < NBLK; i += 256) s += partials[i];
    sbuf[threadIdx.x] = s;
    __syncthreads();
    for (int stride = 128; stride > 0; stride >>= 1) {
        if (threadIdx.x < stride) sbuf[threadIdx.x] += sbuf[threadIdx.x + stride];
        __syncthreads();
    }
    if (threadIdx.x == 0) out[0] = (float)(-sbuf[0] / (double)BB);
}

extern "C" void kernel_launch(void* const* d_in, const int* in_sizes, int n_in,
                              void* d_out, int out_size, void* d_ws, size_t ws_size,
                              hipStream_t stream) {
    const int*   ctx_words = (const int*)  d_in[0];
    const int*   tgt_words = (const int*)  d_in[1];
    const int*   neg_words = (const int*)  d_in[2];
    const float* V_emb     = (const float*)d_in[3];
    const float* U_emb     = (const float*)d_in[4];
    const float* mask_v    = (const float*)d_in[5];
    const float* mask_u    = (const float*)d_in[6];
    const float* mask_neg  = (const float*)d_in[7];
    float*       out       = (float*)d_out;
    double*      partials  = (double*)d_ws;   // needs NBLK*8 = 16 KiB of ws

    cbow_main<<<NBLK, 256, 0, stream>>>(ctx_words, tgt_words, neg_words,
                                        V_emb, U_emb, mask_v, mask_u, mask_neg,
                                        partials);
    cbow_reduce<<<1, 256, 0, stream>>>(partials, out);
}

// Round 5
// 546.601 us; speedup vs baseline: 1.0138x; 1.0006x over previous
//
#include <hip/hip_runtime.h>
#include <math.h>

// Problem constants (CBOW_5205500363137)
#define BB     65536
#define KK     10
#define EE     128
#define NBLK   512    // 2 blocks/CU: fewer concurrent DRAM streams, longer each
#define ITERS  16     // rows per half-wave: 512 * 8 * 16 = 65536

typedef float f4 __attribute__((ext_vector_type(4)));

// Non-temporal (evict-first) load for the use-once mask streams.
__device__ __forceinline__ f4 ldnt(const float* p) {
    return __builtin_nontemporal_load((const f4*)p);
}
// Normal cached load (embedding tables: reused via L2/L3).
__device__ __forceinline__ f4 ldg4(const float* p) {
    return *(const f4*)p;
}

__device__ __forceinline__ float log_sigmoid_f(float x) {
    // log(sigmoid(x)) = min(x, 0) - log1p(exp(-|x|))   (numerically stable)
    return fminf(x, 0.0f) - log1pf(expf(-fabsf(x)));
}

__global__ __launch_bounds__(256) void cbow_main(
    const int*   __restrict__ ctx_words,   // [B]
    const int*   __restrict__ tgt_words,   // [B]
    const int*   __restrict__ neg_words,   // [B,K]
    const float* __restrict__ V_emb,       // [VOCAB,E]
    const float* __restrict__ U_emb,       // [VOCAB,E]
    const float* __restrict__ mask_v,      // [B,E]
    const float* __restrict__ mask_u,      // [B,E]
    const float* __restrict__ mask_neg,    // [B,K,E]
    double*      __restrict__ partials)    // [NBLK]
{
    const int t    = threadIdx.x;
    const int sub  = t >> 5;    // 0..7: half-wave id within block (one row each)
    const int lane = t & 31;    // lane within the 32-lane half-wave

    double local = 0.0;

    for (int gi = 0; gi < ITERS; ++gi) {
        const int row = (blockIdx.x * ITERS + gi) * 8 + sub;

        const int ctx = ctx_words[row];
        const int tgt = tgt_words[row];
        // lanes 0..9 hold the 10 negative indices; broadcast via shfl below
        const int nidx = neg_words[(size_t)row * KK + (lane < KK ? lane : 0)];

        // v = V_emb[ctx] * mask_v[row]   (each lane holds 4 consecutive floats)
        const f4 ve = ldg4(V_emb  + (size_t)ctx * EE + lane * 4);
        const f4 mv = ldnt(mask_v + (size_t)row * EE + lane * 4);
        const f4 v  = ve * mv;

        // u = U_emb[tgt] * mask_u[row]; pos partial = dot(u, v)
        const f4 ue = ldg4(U_emb  + (size_t)tgt * EE + lane * 4);
        const f4 mu = ldnt(mask_u + (size_t)row * EE + lane * 4);
        const f4 up = ue * mu;
        float posp = fmaf(up.x, v.x, fmaf(up.y, v.y, fmaf(up.z, v.z, up.w * v.w)));

        // negp = sum_k dot(U_emb[nk]*mask_neg[row,k], v)
        float negp = 0.0f;
#pragma unroll
        for (int k = 0; k < KK; ++k) {
            const int nk = __shfl(nidx, k, 32);
            const f4 ne = ldg4(U_emb + (size_t)nk * EE + lane * 4);
            const f4 mn = ldnt(mask_neg + ((size_t)row * KK + k) * EE + lane * 4);
            const f4 np = ne * mn;
            negp = fmaf(np.x, v.x, negp);
            negp = fmaf(np.y, v.y, negp);
            negp = fmaf(np.z, v.z, negp);
            negp = fmaf(np.w, v.w, negp);
        }

        // Reduce within the 32-lane half (xor masks <=16 stay inside each half)
        float pos = posp, neg = negp;
#pragma unroll
        for (int m = 16; m >= 1; m >>= 1) {
            pos += __shfl_xor(pos, m, 64);
            neg += __shfl_xor(neg, m, 64);
        }

        if (lane == 0) {
            local += (double)(log_sigmoid_f(pos) + log_sigmoid_f(-neg));
        }
    }

    // Block reduction: 8 half-wave leaders -> one double per block
    __shared__ double sbuf[8];
    if (lane == 0) sbuf[sub] = local;
    __syncthreads();
    if (t == 0) {
        double s = 0.0;
#pragma unroll
        for (int i = 0; i < 8; ++i) s += sbuf[i];
        partials[blockIdx.x] = s;
    }
}

__global__ __launch_bounds__(256) void cbow_reduce(
    const double* __restrict__ partials, float* __restrict__ out)
{
    __shared__ double sbuf[256];
    double s = 0.0;
    for (int i = threadIdx.x; i < NBLK; i += 256) s += partials[i];
    sbuf[threadIdx.x] = s;
    __syncthreads();
    for (int stride = 128; stride > 0; stride >>= 1) {
        if (threadIdx.x < stride) sbuf[threadIdx.x] += sbuf[threadIdx.x + stride];
        __syncthreads();
    }
    if (threadIdx.x == 0) out[0] = (float)(-sbuf[0] / (double)BB);
}

extern "C" void kernel_launch(void* const* d_in, const int* in_sizes, int n_in,
                              void* d_out, int out_size, void* d_ws, size_t ws_size,
                              hipStream_t stream) {
    const int*   ctx_words = (const int*)  d_in[0];
    const int*   tgt_words = (const int*)  d_in[1];
    const int*   neg_words = (const int*)  d_in[2];
    const float* V_emb     = (const float*)d_in[3];
    const float* U_emb     = (const float*)d_in[4];
    const float* mask_v    = (const float*)d_in[5];
    const float* mask_u    = (const float*)d_in[6];
    const float* mask_neg  = (const float*)d_in[7];
    float*       out       = (float*)d_out;
    double*      partials  = (double*)d_ws;   // needs NBLK*8 = 4 KiB of ws

    cbow_main<<<NBLK, 256, 0, stream>>>(ctx_words, tgt_words, neg_words,
                                        V_emb, U_emb, mask_v, mask_u, mask_neg,
                                        partials);
    cbow_reduce<<<1, 256, 0, stream>>>(partials, out);
}